// Round 7
// baseline (188.060 us; speedup 1.0000x reference)
//
#include <hip/hip_runtime.h>
#include <math.h>

// Problem dims
#define NB 64
#define NA 23
#define NT 128
#define ND 256
#define NAE 32
#define NS 6
#define NH 8
#define NDM 288

// Workspace layout (float offsets) — max used 134464 < 135120 budget.
#define OFF_PEK    0        // PEKT[j][t] = sum_e pe[e][t]*Wk[e][j]/sqrt32 : 256*128 (TRANSPOSED)
#define OFF_PECUM  32768    // PEcum[L-1][e] : 128*256 (inclusive prefix over t)
#define OFF_WKT    65536    // WkT[j][e<256] = Wk[e][j]/sqrt32 : 256*256
#define OFF_VWO    131072   // VWo[h][e<256] : 8*256
#define OFF_PEMV   133120   // PEMV[h][t] = sum_e pe[e][t]*VWo[h][e] : 8*128
#define OFF_EVA    134144   // evvA[a][h] : 23*8
#define OFF_CST    134328   // [0..5]=sWf, [6]=b_static.Wg1+bg, [7]=bo.Wg0
#define OFF_SB     134336   // per-b atomic sums : 64
#define OFF_PROBE  134400   // dead sink for the stub (ablation) dispatch : 64

// ---------------- setup1: 393 blocks ----------------
__global__ __launch_bounds__(256) void setup1_kernel(
    const float* __restrict__ Wk, const float* __restrict__ Wv,
    const float* __restrict__ Wo, const float* __restrict__ Wg,
    const float* __restrict__ bv, const float* __restrict__ bo,
    const float* __restrict__ W_static, const float* __restrict__ b_static,
    const float* __restrict__ bg, const float* __restrict__ E_var,
    float* __restrict__ ws)
{
    const int blk = blockIdx.x;
    const int tid = threadIdx.x;
    float* PEcum = ws + OFF_PECUM;
    float* WkT   = ws + OFF_WKT;
    float* VWo   = ws + OFF_VWO;
    float* cst   = ws + OFF_CST;

    if (blk < 128) {
        const int g = tid >> 7, t = tid & 127;
        const int e = blk * 2 + g;
        const int i = e >> 1;
        const float kdiv = 0.07195578415606394f; // ln(10000)/128
        const float dv = expf(-(float)i * kdiv);
        const float ang = (float)t * dv;
        const float v = (e & 1) ? cosf(ang) : sinf(ang);
        __shared__ float buf[256];
        buf[tid] = v;
        #pragma unroll
        for (int s = 1; s < 128; s <<= 1) {
            __syncthreads();
            float add = (t >= s) ? buf[tid - s] : 0.f;
            __syncthreads();
            buf[tid] += add;
        }
        __syncthreads();
        PEcum[t * ND + e] = buf[tid];   // row (L-1) holds sum_{t'<L}
    } else if (blk < 384) {
        const int j = blk - 128;
        const float scale = 0.17677669529663687f;
        WkT[j * 256 + tid] = Wk[tid * ND + j] * scale;
    } else if (blk < 392) {
        const int h = blk - 384;
        __shared__ float wog[32];    // WoWg[h*32+jj]
        __shared__ float vext[32];   // VWo rows 256..287
        __shared__ float vbS;
        {
            const int jj = tid >> 3, sub = tid & 7;
            const int j = h * 32 + jj;
            float acc = 0.f;
            const int m0 = sub * 36;
            #pragma unroll 4
            for (int m = m0; m < m0 + 36; ++m)
                acc = fmaf(Wo[j * NDM + m], Wg[m], acc);
            acc += __shfl_down(acc, 4, 8);
            acc += __shfl_down(acc, 2, 8);
            acc += __shfl_down(acc, 1, 8);
            if (sub == 0) wog[jj] = acc;
        }
        __syncthreads();
        {
            float acc = 0.f;
            #pragma unroll 8
            for (int jj = 0; jj < 32; ++jj)
                acc = fmaf(Wv[tid * ND + h * 32 + jj], wog[jj], acc);
            VWo[h * 256 + tid] = acc;
        }
        if (tid < 32) {
            float acc = 0.f;
            #pragma unroll 8
            for (int jj = 0; jj < 32; ++jj)
                acc = fmaf(Wv[(256 + tid) * ND + h * 32 + jj], wog[jj], acc);
            vext[tid] = acc;
        }
        if (tid == 0) {
            float acc = 0.f;
            #pragma unroll 8
            for (int jj = 0; jj < 32; ++jj)
                acc = fmaf(bv[h * 32 + jj], wog[jj], acc);
            vbS = acc;
        }
        __syncthreads();
        if (tid < NA) {
            float acc = vbS;
            #pragma unroll 8
            for (int ee = 0; ee < 32; ++ee)
                acc = fmaf(E_var[tid * NAE + ee], vext[ee], acc);
            ws[OFF_EVA + tid * NH + h] = acc;
        }
    } else {
        const int i = tid >> 5, sub = tid & 31;
        float acc = 0.f;
        if (i < 6) {
            for (int m = sub; m < 256; m += 32)
                acc = fmaf(W_static[i * ND + m], Wg[NDM + m], acc);
        } else if (i == 6) {
            for (int m = sub; m < 256; m += 32)
                acc = fmaf(b_static[m], Wg[NDM + m], acc);
        } else {
            for (int m = sub; m < NDM; m += 32)
                acc = fmaf(bo[m], Wg[m], acc);
        }
        #pragma unroll
        for (int off = 16; off > 0; off >>= 1)
            acc += __shfl_down(acc, off, 32);
        if (sub == 0) cst[i] = (i == 6) ? acc + bg[0] : acc;
    }
}

// ---------------- setup2: 128 blocks (one per t) ----------------
__global__ __launch_bounds__(256) void setup2_kernel(
    const float* __restrict__ Wk, float* __restrict__ ws)
{
    const int t = blockIdx.x;
    const int tid = threadIdx.x;
    __shared__ float peS[256];
    {
        const int i = tid >> 1;
        const float kdiv = 0.07195578415606394f;
        const float dv = expf(-(float)i * kdiv);
        const float ang = (float)t * dv;
        peS[tid] = (tid & 1) ? cosf(ang) : sinf(ang);
    }
    __syncthreads();
    {   // PEKT[j][t] (transposed so main's qkx loads are lane-coalesced in t)
        float a0 = 0.f, a1 = 0.f, a2 = 0.f, a3 = 0.f;
        #pragma unroll 4
        for (int e = 0; e < 256; e += 4) {
            a0 = fmaf(peS[e],     Wk[ e      * ND + tid], a0);
            a1 = fmaf(peS[e + 1], Wk[(e + 1) * ND + tid], a1);
            a2 = fmaf(peS[e + 2], Wk[(e + 2) * ND + tid], a2);
            a3 = fmaf(peS[e + 3], Wk[(e + 3) * ND + tid], a3);
        }
        const float scale = 0.17677669529663687f;
        ws[OFF_PEK + tid * NT + t] = ((a0 + a1) + (a2 + a3)) * scale;
    }
    {
        const int h = tid >> 5, ee = tid & 31;
        const float* vw = ws + OFF_VWO + h * 256;
        float v = 0.f;
        #pragma unroll
        for (int k = 0; k < 8; ++k)
            v = fmaf(peS[ee + 32 * k], vw[ee + 32 * k], v);
        v += __shfl_down(v, 16, 32);
        v += __shfl_down(v, 8, 32);
        v += __shfl_down(v, 4, 32);
        v += __shfl_down(v, 2, 32);
        v += __shfl_down(v, 1, 32);
        if (ee == 0) ws[OFF_PEMV + h * NT + t] = v;
    }
    if (t == 0 && tid < NB) ws[OFF_SB + tid] = 0.f;   // reset atomic sums
}

// Phase E inner body: KCNT t-values per thread, 4 heads (hh quad), S+M.
#define E_ITER(KCNT) do {                                                    \
    const int e = ebase + ee;                                                \
    const int r = e & 3;                                                     \
    const float2 wb = Wb[half][e];                                           \
    const float4 cq = comboV[e * 4 + (hh ^ r)];                              \
    const float4 cm = comboV[e * 4 + ((2 | hh) ^ r)];                        \
    const float m0 = fmaxf(fmaf(xt0, wb.x, wb.y), 0.f);                      \
    aS[0][0]=fmaf(m0,cq.x,aS[0][0]); aS[0][1]=fmaf(m0,cq.y,aS[0][1]);        \
    aS[0][2]=fmaf(m0,cq.z,aS[0][2]); aS[0][3]=fmaf(m0,cq.w,aS[0][3]);        \
    aM[0][0]=fmaf(m0,cm.x,aM[0][0]); aM[0][1]=fmaf(m0,cm.y,aM[0][1]);        \
    aM[0][2]=fmaf(m0,cm.z,aM[0][2]); aM[0][3]=fmaf(m0,cm.w,aM[0][3]);        \
    const float m1 = fmaxf(fmaf(xt1, wb.x, wb.y), 0.f);                      \
    aS[1][0]=fmaf(m1,cq.x,aS[1][0]); aS[1][1]=fmaf(m1,cq.y,aS[1][1]);        \
    aS[1][2]=fmaf(m1,cq.z,aS[1][2]); aS[1][3]=fmaf(m1,cq.w,aS[1][3]);        \
    aM[1][0]=fmaf(m1,cm.x,aM[1][0]); aM[1][1]=fmaf(m1,cm.y,aM[1][1]);        \
    aM[1][2]=fmaf(m1,cm.z,aM[1][2]); aM[1][3]=fmaf(m1,cm.w,aM[1][3]);        \
    if ((KCNT) == 4) {                                                       \
        const float m2 = fmaxf(fmaf(xt2, wb.x, wb.y), 0.f);                  \
        aS[2][0]=fmaf(m2,cq.x,aS[2][0]); aS[2][1]=fmaf(m2,cq.y,aS[2][1]);    \
        aS[2][2]=fmaf(m2,cq.z,aS[2][2]); aS[2][3]=fmaf(m2,cq.w,aS[2][3]);    \
        aM[2][0]=fmaf(m2,cm.x,aM[2][0]); aM[2][1]=fmaf(m2,cm.y,aM[2][1]);    \
        aM[2][2]=fmaf(m2,cm.z,aM[2][2]); aM[2][3]=fmaf(m2,cm.w,aM[2][3]);    \
        const float m3 = fmaxf(fmaf(xt3, wb.x, wb.y), 0.f);                  \
        aS[3][0]=fmaf(m3,cq.x,aS[3][0]); aS[3][1]=fmaf(m3,cq.y,aS[3][1]);    \
        aS[3][2]=fmaf(m3,cq.z,aS[3][2]); aS[3][3]=fmaf(m3,cq.w,aS[3][3]);    \
        aM[3][0]=fmaf(m3,cm.x,aM[3][0]); aM[3][1]=fmaf(m3,cm.y,aM[3][1]);    \
        aM[3][2]=fmaf(m3,cm.z,aM[3][2]); aM[3][3]=fmaf(m3,cm.w,aM[3][3]);    \
    }                                                                        \
} while (0)

// ---------------- main: one block = TWO wg's; stub=1 skips Phase E (ablation) ----------------
__global__ __launch_bounds__(512) void main_kernel(
    const float* __restrict__ data, const int* __restrict__ lengths,
    const float* __restrict__ W_embed, const float* __restrict__ b_embed,
    const float* __restrict__ E_var,
    const float* __restrict__ Wq, const float* __restrict__ bq,
    float* __restrict__ ws, const int stub)
{
    const int pair = blockIdx.x;          // 736 pairs
    const int tid  = threadIdx.x;         // 0..511
    const int half = tid >> 8;
    const int lt   = tid & 255;
    const int wgh  = pair * 2 + half;
    const int ah   = wgh % NA;
    const int bh   = wgh / NA;
    const int Lh   = lengths[wgh];        // uniform across the half's 4 waves

    __shared__ __align__(16) float xs[2][NT];
    __shared__ __align__(16) float ag[2][NDM];
    __shared__ __align__(16) float qs[2][ND];
    __shared__ float2 Wb[2][ND];
    // combo[w]: row e = 4 float4s {qk h0-3, qk h4-7, VWo h0-3, VWo h4-7},
    // XOR-swizzled (slot q^(e&3)). [0,2048) reused as sc/mvb after Phase E.
    __shared__ __align__(16) float combo[2][ND * 16];
    __shared__ __align__(16) float qkx[2][NH * NT];
    __shared__ float red[2][4];

    const float* PEcum = ws + OFF_PECUM;
    const float* WkT   = ws + OFF_WKT;
    const float* VWo   = ws + OFF_VWO;
    const float* cstp  = ws + OFF_CST;

    // ---- Phase A (per half): float4 xs broadcasts ----
    if (lt < NT) xs[half][lt] = data[wgh * NT + lt];
    __syncthreads();
    {
        const int e = lt;
        if (Lh > 0) {
            const float We = W_embed[ah * ND + e];
            const float be = b_embed[ah * ND + e];
            Wb[half][e] = make_float2(We, be);
            const float4* x4 = (const float4*)xs[half];
            float s0 = 0.f, s1 = 0.f, s2 = 0.f, s3 = 0.f;
            const int nq = Lh >> 2;
            for (int q = 0; q < nq; ++q) {
                const float4 xv = x4[q];
                s0 += fmaxf(fmaf(xv.x, We, be), 0.f);
                s1 += fmaxf(fmaf(xv.y, We, be), 0.f);
                s2 += fmaxf(fmaf(xv.z, We, be), 0.f);
                s3 += fmaxf(fmaf(xv.w, We, be), 0.f);
            }
            for (int t = nq * 4; t < Lh; ++t)
                s0 += fmaxf(fmaf(xs[half][t], We, be), 0.f);
            ag[half][e] = (((s0 + s1) + (s2 + s3)) + PEcum[(Lh - 1) * ND + e]) / (float)Lh;
        } else {
            Wb[half][e] = make_float2(0.f, 0.f);
            ag[half][e] = 0.f;
        }
    }
    if (lt < NAE) ag[half][ND + lt] = (Lh > 0) ? E_var[ah * NAE + lt] : 0.f;
    __syncthreads();

    // ---- Phase C: q for both wgs, Wq element read once; float4 ag broadcasts ----
    {
        const int j = lt;
        const float4* a40 = (const float4*)ag[0];
        const float4* a41 = (const float4*)ag[1];
        const int fi0 = half * 36;           // 288 floats = 72 float4s; half covers 36
        float c0 = 0.f, c1 = 0.f, c2 = 0.f, c3 = 0.f;
        #pragma unroll 4
        for (int fi = fi0; fi < fi0 + 36; ++fi) {
            const float4 av0 = a40[fi];
            const float4 av1 = a41[fi];
            const int f = fi * 4;
            const float w0 = Wq[ f      * ND + j];
            const float w1 = Wq[(f + 1) * ND + j];
            const float w2 = Wq[(f + 2) * ND + j];
            const float w3 = Wq[(f + 3) * ND + j];
            c0 = fmaf(av0.x, w0, c0); c2 = fmaf(av0.y, w1, c2);
            c0 = fmaf(av0.z, w2, c0); c2 = fmaf(av0.w, w3, c2);
            c1 = fmaf(av1.x, w0, c1); c3 = fmaf(av1.y, w1, c3);
            c1 = fmaf(av1.z, w2, c1); c3 = fmaf(av1.w, w3, c3);
        }
        float* Csc = &combo[0][0];           // scratch[half][wg][j]
        Csc[half * 512 +       j] = c0 + c2;
        Csc[half * 512 + 256 + j] = c1 + c3;
    }
    __syncthreads();
    {
        const float* Csc = &combo[0][0];
        qs[half][lt] = bq[lt] + Csc[half * 256 + lt] + Csc[512 + half * 256 + lt];
    }
    __syncthreads();

    // ---- Phase D: qk rows for both wgs; q via float4 broadcasts ----
    {
        const int e = lt;
        const int hb = half;                 // heads hb*4 .. hb*4+3
        const float* wr = WkT + (hb * 128) * 256 + e;   // lane-coalesced columns
        const float4* q40 = (const float4*)(qs[0] + hb * 128);
        const float4* q41 = (const float4*)(qs[1] + hb * 128);
        float qk0[4], qk1[4];
        #pragma unroll
        for (int h4 = 0; h4 < 4; ++h4) {
            float c00 = 0.f, c01 = 0.f, c10 = 0.f, c11 = 0.f;
            #pragma unroll
            for (int jq = 0; jq < 8; ++jq) {
                const float4 q0 = q40[h4 * 8 + jq];
                const float4 q1 = q41[h4 * 8 + jq];
                const float w0 = wr[(h4 * 32 + jq * 4 + 0) * 256];
                const float w1 = wr[(h4 * 32 + jq * 4 + 1) * 256];
                const float w2 = wr[(h4 * 32 + jq * 4 + 2) * 256];
                const float w3 = wr[(h4 * 32 + jq * 4 + 3) * 256];
                c00 = fmaf(w0, q0.x, c00); c01 = fmaf(w1, q0.y, c01);
                c00 = fmaf(w2, q0.z, c00); c01 = fmaf(w3, q0.w, c01);
                c10 = fmaf(w0, q1.x, c10); c11 = fmaf(w1, q1.y, c11);
                c10 = fmaf(w2, q1.z, c10); c11 = fmaf(w3, q1.w, c11);
            }
            qk0[h4] = c00 + c01;
            qk1[h4] = c10 + c11;
        }
        const int r = e & 3;
        float4* row0 = (float4*)(&combo[0][0]) + e * 4;
        float4* row1 = (float4*)(&combo[1][0]) + e * 4;
        row0[hb ^ r] = make_float4(qk0[0], qk0[1], qk0[2], qk0[3]);
        row1[hb ^ r] = make_float4(qk1[0], qk1[1], qk1[2], qk1[3]);
        const float4 vw = make_float4(VWo[(hb * 4 + 0) * 256 + e],
                                      VWo[(hb * 4 + 1) * 256 + e],
                                      VWo[(hb * 4 + 2) * 256 + e],
                                      VWo[(hb * 4 + 3) * 256 + e]);
        row0[(2 | hb) ^ r] = vw;
        row1[(2 | hb) ^ r] = vw;
    }
    // ---- qkx from PEKT (coalesced in t), both wgs per read ----
    {
        const int h  = tid >> 6;             // 0..7
        const int tq = tid & 63;
        const float* pekt = ws + OFF_PEK;    // PEKT[j][t]
        const float4* qs40 = (const float4*)(qs[0] + h * 32);
        const float4* qs41 = (const float4*)(qs[1] + h * 32);
        float b00 = 0.f, b01 = 0.f, b10 = 0.f, b11 = 0.f;  // [wg][t-half]
        #pragma unroll
        for (int jq = 0; jq < 8; ++jq) {
            const float4 q0 = qs40[jq];
            const float4 q1 = qs41[jq];
            const float* pr = pekt + (h * 32 + jq * 4) * NT + tq;
            const float p00 = pr[0];          const float p01 = pr[64];
            const float p10 = pr[NT];         const float p11 = pr[NT + 64];
            const float p20 = pr[2 * NT];     const float p21 = pr[2 * NT + 64];
            const float p30 = pr[3 * NT];     const float p31 = pr[3 * NT + 64];
            b00 = fmaf(q0.x, p00, b00); b00 = fmaf(q0.y, p10, b00);
            b00 = fmaf(q0.z, p20, b00); b00 = fmaf(q0.w, p30, b00);
            b01 = fmaf(q0.x, p01, b01); b01 = fmaf(q0.y, p11, b01);
            b01 = fmaf(q0.z, p21, b01); b01 = fmaf(q0.w, p31, b01);
            b10 = fmaf(q1.x, p00, b10); b10 = fmaf(q1.y, p10, b10);
            b10 = fmaf(q1.z, p20, b10); b10 = fmaf(q1.w, p30, b10);
            b11 = fmaf(q1.x, p01, b11); b11 = fmaf(q1.y, p11, b11);
            b11 = fmaf(q1.z, p21, b11); b11 = fmaf(q1.w, p31, b11);
        }
        qkx[0][h * NT + tq]      = b00;
        qkx[0][h * NT + tq + 64] = b01;
        qkx[1][h * NT + tq]      = b10;
        qkx[1][h * NT + tq + 64] = b11;
    }
    __syncthreads();

    // ---- Phase E: t-quad x e-chunk-in-wave; combine via shfl (no LDS partials) ----
    {
        const int lane = lt & 63;
        const int wv   = lt >> 6;        // wave id within half: 0..3
        const int hh   = wv & 1;         // head-quad
        const int tw   = wv >> 1;        // t-window
        const int t0   = lane & 15;
        const int c    = lane >> 4;      // e-chunk 0..3 (within wave)
        const int tb   = tw * 16 + t0;   // [0,32)
        const int ebase = c * 64;
        const float4* comboV = (const float4*)(&combo[half][0]);
        float aS[4][4], aM[4][4];
        #pragma unroll
        for (int k = 0; k < 4; ++k)
            #pragma unroll
            for (int j = 0; j < 4; ++j) { aS[k][j] = 0.f; aM[k][j] = 0.f; }
        const float xt0 = xs[half][tb];
        const float xt1 = xs[half][tb + 32];
        const float xt2 = xs[half][tb + 64];
        const float xt3 = xs[half][tb + 96];
        if (!stub && Lh > 64) {
            #pragma unroll 4
            for (int ee = 0; ee < 64; ++ee) E_ITER(4);
        } else if (!stub && Lh > 0) {
            // t >= 64 always masked in Phase F -> K=2 (t < 64 only)
            #pragma unroll 4
            for (int ee = 0; ee < 64; ++ee) E_ITER(2);
        }
        // sum across e-chunks c=0..3: lane = c*16+t0 -> shfl_down 32 then 16
        #pragma unroll
        for (int k = 0; k < 4; ++k)
            #pragma unroll
            for (int j = 0; j < 4; ++j) {
                float vS = aS[k][j], vM = aM[k][j];
                vS += __shfl_down(vS, 32, 64);
                vS += __shfl_down(vS, 16, 64);
                vM += __shfl_down(vM, 32, 64);
                vM += __shfl_down(vM, 16, 64);
                aS[k][j] = vS; aM[k][j] = vM;
            }
        __syncthreads();   // all combo reads done -> reuse region
        float* scF = &combo[half][0];        // sc[h*128+t]
        float* mvF = scF + 1024;             // mvb[h*128+t]
        if (c == 0) {
            #pragma unroll
            for (int k = 0; k < 4; ++k)
                #pragma unroll
                for (int j = 0; j < 4; ++j) {
                    const int h = hh * 4 + j;
                    scF[h * NT + tb + 32 * k] = aS[k][j];
                    mvF[h * NT + tb + 32 * k] = aM[k][j];
                }
        }
    }
    __syncthreads();

    // ---- Phase F (per half): softmax over t<Lh with pe corrections ----
    if (Lh > 0) {
        const float* sc   = &combo[half][0];
        const float* mvb  = sc + 1024;
        const float* pemv = ws + OFF_PEMV;
        const int wv = lt >> 6, lane = lt & 63;
        float wsum = 0.f;
        for (int hh2 = 0; hh2 < 2; ++hh2) {
            const int h = wv * 2 + hh2;
            float s1 = (lane < Lh) ? sc[h * NT + lane] + qkx[half][h * NT + lane] : -3e38f;
            float s2 = (lane + 64 < Lh) ? sc[h * NT + 64 + lane] + qkx[half][h * NT + 64 + lane] : -3e38f;
            float mx = fmaxf(s1, s2);
            #pragma unroll
            for (int off = 32; off > 0; off >>= 1)
                mx = fmaxf(mx, __shfl_down(mx, off, 64));
            mx = __shfl(mx, 0, 64);
            const float vbv = ws[OFF_EVA + ah * NH + h];
            float e1 = (lane < Lh) ? __expf(s1 - mx) : 0.f;
            float e2 = (lane + 64 < Lh) ? __expf(s2 - mx) : 0.f;
            float num = e1 * (mvb[h * NT + lane] + pemv[h * NT + lane] + vbv);
            num = fmaf(e2, mvb[h * NT + 64 + lane] + pemv[h * NT + 64 + lane] + vbv, num);
            float den = e1 + e2;
            #pragma unroll
            for (int off = 32; off > 0; off >>= 1) {
                num += __shfl_down(num, off, 64);
                den += __shfl_down(den, off, 64);
            }
            if (lane == 0) wsum += num / den;
        }
        if (lane == 0) red[half][wv] = wsum;
    }
    __syncthreads();
    if (lt == 0 && Lh > 0) {
        float* sbase = ws + (stub ? OFF_PROBE : OFF_SB);
        atomicAdd(sbase + bh,
                  cstp[7] + red[half][0] + red[half][1] + red[half][2] + red[half][3]);
    }
}

__global__ __launch_bounds__(64) void final_kernel(
    const float* __restrict__ statics, const int* __restrict__ lengths,
    const float* __restrict__ ws, float* __restrict__ out)
{
    const int b = threadIdx.x;   // 64 threads, one per batch
    const float* cst = ws + OFF_CST;
    int n = 0;
    for (int a = 0; a < NA; ++a)
        if (lengths[b * NA + a] > 0) ++n;
    float o = ws[OFF_SB + b] / ((float)n + 1e-9f);
    #pragma unroll
    for (int i = 0; i < NS; ++i)
        o = fmaf(statics[b * NS + i], cst[i], o);
    o += cst[6];
    out[b] = o;
}

extern "C" void kernel_launch(void* const* d_in, const int* in_sizes, int n_in,
                              void* d_out, int out_size, void* d_ws, size_t ws_size,
                              hipStream_t stream) {
    const float* data     = (const float*)d_in[0];
    // d_in[1] = time  (implied by mask; unused)
    const int*   mask     = (const int*)d_in[2];
    const float* statics  = (const float*)d_in[3];
    const float* W_embed  = (const float*)d_in[4];
    const float* b_embed  = (const float*)d_in[5];
    const float* E_var    = (const float*)d_in[6];
    const float* W_static = (const float*)d_in[7];
    const float* b_static = (const float*)d_in[8];
    const float* Wq       = (const float*)d_in[9];
    const float* bq       = (const float*)d_in[10];
    const float* Wk       = (const float*)d_in[11];
    // d_in[12] = bk (uniform over t -> cancels in softmax; unused)
    const float* Wv       = (const float*)d_in[13];
    const float* bv       = (const float*)d_in[14];
    const float* Wo       = (const float*)d_in[15];
    const float* bo       = (const float*)d_in[16];
    const float* Wg       = (const float*)d_in[17];
    const float* bg       = (const float*)d_in[18];
    float* out = (float*)d_out;
    float* ws  = (float*)d_ws;

    setup1_kernel<<<dim3(393), dim3(256), 0, stream>>>(Wk, Wv, Wo, Wg, bv, bo,
                                                       W_static, b_static, bg, E_var, ws);
    setup2_kernel<<<dim3(128), dim3(256), 0, stream>>>(Wk, ws);
    main_kernel<<<dim3(NB * NA / 2), dim3(512), 0, stream>>>(data, mask, W_embed, b_embed,
                                                             E_var, Wq, bq, ws, 0);
    final_kernel<<<dim3(1), dim3(64), 0, stream>>>(statics, mask, ws, out);
    // Ablation probe (one-round instrumentation): identical kernel, Phase E
    // skipped, results sunk to OFF_PROBE (unread). Measures the A-D+F floor.
    main_kernel<<<dim3(NB * NA / 2), dim3(512), 0, stream>>>(data, mask, W_embed, b_embed,
                                                             E_var, Wq, bq, ws, 1);
}

// Round 8
// 149.978 us; speedup vs baseline: 1.2539x; 1.2539x over previous
//
#include <hip/hip_runtime.h>
#include <math.h>

// Problem dims
#define NB 64
#define NA 23
#define NT 128
#define ND 256
#define NAE 32
#define NS 6
#define NH 8
#define NDM 288

// Workspace layout (float offsets) — max used 134400 < 135120 budget.
#define OFF_PEK    0        // PEKT[j][t] = sum_e pe[e][t]*Wk[e][j]/sqrt32 : 256*128 (TRANSPOSED)
#define OFF_PECUM  32768    // PEcum[L-1][e] : 128*256 (inclusive prefix over t)
#define OFF_WKT    65536    // WkT[j][e<256] = Wk[e][j]/sqrt32 : 256*256
#define OFF_VWO    131072   // VWo[h][e<256] : 8*256
#define OFF_PEMV   133120   // PEMV[h][t] = sum_e pe[e][t]*VWo[h][e] : 8*128
#define OFF_EVA    134144   // evvA[a][h] : 23*8
#define OFF_CST    134328   // [0..5]=sWf, [6]=b_static.Wg1+bg, [7]=bo.Wg0
#define OFF_SB     134336   // per-b atomic sums : 64

// ---------------- setup1: 393 blocks ----------------
__global__ __launch_bounds__(256) void setup1_kernel(
    const float* __restrict__ Wk, const float* __restrict__ Wv,
    const float* __restrict__ Wo, const float* __restrict__ Wg,
    const float* __restrict__ bv, const float* __restrict__ bo,
    const float* __restrict__ W_static, const float* __restrict__ b_static,
    const float* __restrict__ bg, const float* __restrict__ E_var,
    float* __restrict__ ws)
{
    const int blk = blockIdx.x;
    const int tid = threadIdx.x;
    float* PEcum = ws + OFF_PECUM;
    float* WkT   = ws + OFF_WKT;
    float* VWo   = ws + OFF_VWO;
    float* cst   = ws + OFF_CST;

    if (blk < 128) {
        const int g = tid >> 7, t = tid & 127;
        const int e = blk * 2 + g;
        const int i = e >> 1;
        const float kdiv = 0.07195578415606394f; // ln(10000)/128
        const float dv = expf(-(float)i * kdiv);
        const float ang = (float)t * dv;
        const float v = (e & 1) ? cosf(ang) : sinf(ang);
        __shared__ float buf[256];
        buf[tid] = v;
        #pragma unroll
        for (int s = 1; s < 128; s <<= 1) {
            __syncthreads();
            float add = (t >= s) ? buf[tid - s] : 0.f;
            __syncthreads();
            buf[tid] += add;
        }
        __syncthreads();
        PEcum[t * ND + e] = buf[tid];   // row (L-1) holds sum_{t'<L}
    } else if (blk < 384) {
        const int j = blk - 128;
        const float scale = 0.17677669529663687f;
        WkT[j * 256 + tid] = Wk[tid * ND + j] * scale;
    } else if (blk < 392) {
        const int h = blk - 384;
        __shared__ float wog[32];    // WoWg[h*32+jj]
        __shared__ float vext[32];   // VWo rows 256..287
        __shared__ float vbS;
        {
            const int jj = tid >> 3, sub = tid & 7;
            const int j = h * 32 + jj;
            float acc = 0.f;
            const int m0 = sub * 36;
            #pragma unroll 4
            for (int m = m0; m < m0 + 36; ++m)
                acc = fmaf(Wo[j * NDM + m], Wg[m], acc);
            acc += __shfl_down(acc, 4, 8);
            acc += __shfl_down(acc, 2, 8);
            acc += __shfl_down(acc, 1, 8);
            if (sub == 0) wog[jj] = acc;
        }
        __syncthreads();
        {
            float acc = 0.f;
            #pragma unroll 8
            for (int jj = 0; jj < 32; ++jj)
                acc = fmaf(Wv[tid * ND + h * 32 + jj], wog[jj], acc);
            VWo[h * 256 + tid] = acc;
        }
        if (tid < 32) {
            float acc = 0.f;
            #pragma unroll 8
            for (int jj = 0; jj < 32; ++jj)
                acc = fmaf(Wv[(256 + tid) * ND + h * 32 + jj], wog[jj], acc);
            vext[tid] = acc;
        }
        if (tid == 0) {
            float acc = 0.f;
            #pragma unroll 8
            for (int jj = 0; jj < 32; ++jj)
                acc = fmaf(bv[h * 32 + jj], wog[jj], acc);
            vbS = acc;
        }
        __syncthreads();
        if (tid < NA) {
            float acc = vbS;
            #pragma unroll 8
            for (int ee = 0; ee < 32; ++ee)
                acc = fmaf(E_var[tid * NAE + ee], vext[ee], acc);
            ws[OFF_EVA + tid * NH + h] = acc;
        }
    } else {
        const int i = tid >> 5, sub = tid & 31;
        float acc = 0.f;
        if (i < 6) {
            for (int m = sub; m < 256; m += 32)
                acc = fmaf(W_static[i * ND + m], Wg[NDM + m], acc);
        } else if (i == 6) {
            for (int m = sub; m < 256; m += 32)
                acc = fmaf(b_static[m], Wg[NDM + m], acc);
        } else {
            for (int m = sub; m < NDM; m += 32)
                acc = fmaf(bo[m], Wg[m], acc);
        }
        #pragma unroll
        for (int off = 16; off > 0; off >>= 1)
            acc += __shfl_down(acc, off, 32);
        if (sub == 0) cst[i] = (i == 6) ? acc + bg[0] : acc;
    }
}

// ---------------- setup2: 128 blocks (one per t) ----------------
__global__ __launch_bounds__(256) void setup2_kernel(
    const float* __restrict__ Wk, float* __restrict__ ws)
{
    const int t = blockIdx.x;
    const int tid = threadIdx.x;
    __shared__ float peS[256];
    {
        const int i = tid >> 1;
        const float kdiv = 0.07195578415606394f;
        const float dv = expf(-(float)i * kdiv);
        const float ang = (float)t * dv;
        peS[tid] = (tid & 1) ? cosf(ang) : sinf(ang);
    }
    __syncthreads();
    {   // PEKT[j][t] (transposed so main's qkx loads are lane-coalesced in t)
        float a0 = 0.f, a1 = 0.f, a2 = 0.f, a3 = 0.f;
        #pragma unroll 4
        for (int e = 0; e < 256; e += 4) {
            a0 = fmaf(peS[e],     Wk[ e      * ND + tid], a0);
            a1 = fmaf(peS[e + 1], Wk[(e + 1) * ND + tid], a1);
            a2 = fmaf(peS[e + 2], Wk[(e + 2) * ND + tid], a2);
            a3 = fmaf(peS[e + 3], Wk[(e + 3) * ND + tid], a3);
        }
        const float scale = 0.17677669529663687f;
        ws[OFF_PEK + tid * NT + t] = ((a0 + a1) + (a2 + a3)) * scale;
    }
    {
        const int h = tid >> 5, ee = tid & 31;
        const float* vw = ws + OFF_VWO + h * 256;
        float v = 0.f;
        #pragma unroll
        for (int k = 0; k < 8; ++k)
            v = fmaf(peS[ee + 32 * k], vw[ee + 32 * k], v);
        v += __shfl_down(v, 16, 32);
        v += __shfl_down(v, 8, 32);
        v += __shfl_down(v, 4, 32);
        v += __shfl_down(v, 2, 32);
        v += __shfl_down(v, 1, 32);
        if (ee == 0) ws[OFF_PEMV + h * NT + t] = v;
    }
    if (t == 0 && tid < NB) ws[OFF_SB + tid] = 0.f;   // reset atomic sums
}

// Phase E inner body: KCNT t-values per thread, 4 heads (hh quad), S+M.
// Swizzle r = (e + (e>>6)) & 3: per-wave store pattern identical to the
// r2-measured r=e&3 (e>>6 is wave-constant in D), but in E the 4 e-chunk
// read groups (c = e>>6) get DISTINCT slots -> conflict-free broadcasts.
#define E_ITER(KCNT) do {                                                    \
    const int e = ebase + ee;                                                \
    const int r = (e + (e >> 6)) & 3;                                        \
    const float2 wb = Wb[half][e + (e >> 6)];                                \
    const float4 cq = comboV[e * 4 + (hh ^ r)];                              \
    const float4 cm = comboV[e * 4 + ((2 | hh) ^ r)];                        \
    const float m0 = fmaxf(fmaf(xt0, wb.x, wb.y), 0.f);                      \
    aS[0][0]=fmaf(m0,cq.x,aS[0][0]); aS[0][1]=fmaf(m0,cq.y,aS[0][1]);        \
    aS[0][2]=fmaf(m0,cq.z,aS[0][2]); aS[0][3]=fmaf(m0,cq.w,aS[0][3]);        \
    aM[0][0]=fmaf(m0,cm.x,aM[0][0]); aM[0][1]=fmaf(m0,cm.y,aM[0][1]);        \
    aM[0][2]=fmaf(m0,cm.z,aM[0][2]); aM[0][3]=fmaf(m0,cm.w,aM[0][3]);        \
    const float m1 = fmaxf(fmaf(xt1, wb.x, wb.y), 0.f);                      \
    aS[1][0]=fmaf(m1,cq.x,aS[1][0]); aS[1][1]=fmaf(m1,cq.y,aS[1][1]);        \
    aS[1][2]=fmaf(m1,cq.z,aS[1][2]); aS[1][3]=fmaf(m1,cq.w,aS[1][3]);        \
    aM[1][0]=fmaf(m1,cm.x,aM[1][0]); aM[1][1]=fmaf(m1,cm.y,aM[1][1]);        \
    aM[1][2]=fmaf(m1,cm.z,aM[1][2]); aM[1][3]=fmaf(m1,cm.w,aM[1][3]);        \
    if ((KCNT) == 4) {                                                       \
        const float m2 = fmaxf(fmaf(xt2, wb.x, wb.y), 0.f);                  \
        aS[2][0]=fmaf(m2,cq.x,aS[2][0]); aS[2][1]=fmaf(m2,cq.y,aS[2][1]);    \
        aS[2][2]=fmaf(m2,cq.z,aS[2][2]); aS[2][3]=fmaf(m2,cq.w,aS[2][3]);    \
        aM[2][0]=fmaf(m2,cm.x,aM[2][0]); aM[2][1]=fmaf(m2,cm.y,aM[2][1]);    \
        aM[2][2]=fmaf(m2,cm.z,aM[2][2]); aM[2][3]=fmaf(m2,cm.w,aM[2][3]);    \
        const float m3 = fmaxf(fmaf(xt3, wb.x, wb.y), 0.f);                  \
        aS[3][0]=fmaf(m3,cq.x,aS[3][0]); aS[3][1]=fmaf(m3,cq.y,aS[3][1]);    \
        aS[3][2]=fmaf(m3,cq.z,aS[3][2]); aS[3][3]=fmaf(m3,cq.w,aS[3][3]);    \
        aM[3][0]=fmaf(m3,cm.x,aM[3][0]); aM[3][1]=fmaf(m3,cm.y,aM[3][1]);    \
        aM[3][2]=fmaf(m3,cm.z,aM[3][2]); aM[3][3]=fmaf(m3,cm.w,aM[3][3]);    \
    }                                                                        \
} while (0)

// ---------------- main: one block = TWO wg's ----------------
// LDS budget 40,032 B -> 4 blocks/CU (32 waves, full occupancy).
// Aliases: ag lives in combo[1][0..576) (dead before Phase D overwrites);
// qkx computed post-E into combo[half][2048..3072) (rows dead; sc/mvb use [0,2048)).
__global__ __launch_bounds__(512) void main_kernel(
    const float* __restrict__ data, const int* __restrict__ lengths,
    const float* __restrict__ W_embed, const float* __restrict__ b_embed,
    const float* __restrict__ E_var,
    const float* __restrict__ Wq, const float* __restrict__ bq,
    float* __restrict__ ws)
{
    const int pair = blockIdx.x;          // 736 pairs
    const int tid  = threadIdx.x;         // 0..511
    const int half = tid >> 8;
    const int lt   = tid & 255;
    const int wgh  = pair * 2 + half;
    const int ah   = wgh % NA;
    const int bh   = wgh / NA;
    const int Lh   = lengths[wgh];        // uniform across the half's 4 waves

    __shared__ __align__(16) float xs[2][NT];
    __shared__ __align__(16) float qs[2][ND];
    __shared__ float2 Wb[2][ND + 4];      // padded index e+(e>>6): chunk groups hit distinct banks
    // combo[w]: rows e = 4 float4s {qk h0-3, qk h4-7, VWo h0-3, VWo h4-7}, swizzled.
    // Also: combo[0][0..1024) = Phase-C scratch; combo[1][0..576) = ag alias;
    // after E: [0,1024)=sc, [1024,2048)=mvb, [2048,3072)=qkx per half.
    __shared__ __align__(16) float combo[2][ND * 16];
    __shared__ float red[2][4];

    const float* PEcum = ws + OFF_PECUM;
    const float* WkT   = ws + OFF_WKT;
    const float* VWo   = ws + OFF_VWO;
    const float* cstp  = ws + OFF_CST;
    float* agA = &combo[1][0];            // ag[w][f] = agA[w*NDM + f]

    // ---- Phase A (per half) ----
    if (lt < NT) xs[half][lt] = data[wgh * NT + lt];
    __syncthreads();
    {
        const int e = lt;
        if (Lh > 0) {
            const float We = W_embed[ah * ND + e];
            const float be = b_embed[ah * ND + e];
            Wb[half][e + (e >> 6)] = make_float2(We, be);
            const float4* x4 = (const float4*)xs[half];
            float s0 = 0.f, s1 = 0.f, s2 = 0.f, s3 = 0.f;
            const int nq = Lh >> 2;
            for (int q = 0; q < nq; ++q) {
                const float4 xv = x4[q];
                s0 += fmaxf(fmaf(xv.x, We, be), 0.f);
                s1 += fmaxf(fmaf(xv.y, We, be), 0.f);
                s2 += fmaxf(fmaf(xv.z, We, be), 0.f);
                s3 += fmaxf(fmaf(xv.w, We, be), 0.f);
            }
            for (int t = nq * 4; t < Lh; ++t)
                s0 += fmaxf(fmaf(xs[half][t], We, be), 0.f);
            agA[half * NDM + e] = (((s0 + s1) + (s2 + s3)) + PEcum[(Lh - 1) * ND + e]) / (float)Lh;
        } else {
            Wb[half][e + (e >> 6)] = make_float2(0.f, 0.f);
            agA[half * NDM + e] = 0.f;
        }
    }
    if (lt < NAE) agA[half * NDM + ND + lt] = (Lh > 0) ? E_var[ah * NAE + lt] : 0.f;
    __syncthreads();

    // ---- Phase C: q for both wgs, Wq element read once; float4 ag broadcasts ----
    {
        const int j = lt;
        const float4* a40 = (const float4*)(agA);
        const float4* a41 = (const float4*)(agA + NDM);
        const int fi0 = half * 36;           // 288 floats = 72 float4s; half covers 36
        float c0 = 0.f, c1 = 0.f, c2 = 0.f, c3 = 0.f;
        #pragma unroll 4
        for (int fi = fi0; fi < fi0 + 36; ++fi) {
            const float4 av0 = a40[fi];
            const float4 av1 = a41[fi];
            const int f = fi * 4;
            const float w0 = Wq[ f      * ND + j];
            const float w1 = Wq[(f + 1) * ND + j];
            const float w2 = Wq[(f + 2) * ND + j];
            const float w3 = Wq[(f + 3) * ND + j];
            c0 = fmaf(av0.x, w0, c0); c2 = fmaf(av0.y, w1, c2);
            c0 = fmaf(av0.z, w2, c0); c2 = fmaf(av0.w, w3, c2);
            c1 = fmaf(av1.x, w0, c1); c3 = fmaf(av1.y, w1, c3);
            c1 = fmaf(av1.z, w2, c1); c3 = fmaf(av1.w, w3, c3);
        }
        float* Csc = &combo[0][0];           // scratch[half][wg][j] (disjoint from ag alias)
        Csc[half * 512 +       j] = c0 + c2;
        Csc[half * 512 + 256 + j] = c1 + c3;
    }
    __syncthreads();
    {
        const float* Csc = &combo[0][0];
        qs[half][lt] = bq[lt] + Csc[half * 256 + lt] + Csc[512 + half * 256 + lt];
    }
    __syncthreads();

    // ---- Phase D: qk rows for both wgs (overwrites C scratch + ag alias) ----
    {
        const int e = lt;
        const int hb = half;                 // heads hb*4 .. hb*4+3
        const float* wr = WkT + (hb * 128) * 256 + e;   // lane-coalesced columns
        const float4* q40 = (const float4*)(qs[0] + hb * 128);
        const float4* q41 = (const float4*)(qs[1] + hb * 128);
        float qk0[4], qk1[4];
        #pragma unroll
        for (int h4 = 0; h4 < 4; ++h4) {
            float c00 = 0.f, c01 = 0.f, c10 = 0.f, c11 = 0.f;
            #pragma unroll
            for (int jq = 0; jq < 8; ++jq) {
                const float4 q0 = q40[h4 * 8 + jq];
                const float4 q1 = q41[h4 * 8 + jq];
                const float w0 = wr[(h4 * 32 + jq * 4 + 0) * 256];
                const float w1 = wr[(h4 * 32 + jq * 4 + 1) * 256];
                const float w2 = wr[(h4 * 32 + jq * 4 + 2) * 256];
                const float w3 = wr[(h4 * 32 + jq * 4 + 3) * 256];
                c00 = fmaf(w0, q0.x, c00); c01 = fmaf(w1, q0.y, c01);
                c00 = fmaf(w2, q0.z, c00); c01 = fmaf(w3, q0.w, c01);
                c10 = fmaf(w0, q1.x, c10); c11 = fmaf(w1, q1.y, c11);
                c10 = fmaf(w2, q1.z, c10); c11 = fmaf(w3, q1.w, c11);
            }
            qk0[h4] = c00 + c01;
            qk1[h4] = c10 + c11;
        }
        const int r = (e + (e >> 6)) & 3;    // e>>6 wave-constant here: store pattern == r2-measured
        float4* row0 = (float4*)(&combo[0][0]) + e * 4;
        float4* row1 = (float4*)(&combo[1][0]) + e * 4;
        row0[hb ^ r] = make_float4(qk0[0], qk0[1], qk0[2], qk0[3]);
        row1[hb ^ r] = make_float4(qk1[0], qk1[1], qk1[2], qk1[3]);
        const float4 vw = make_float4(VWo[(hb * 4 + 0) * 256 + e],
                                      VWo[(hb * 4 + 1) * 256 + e],
                                      VWo[(hb * 4 + 2) * 256 + e],
                                      VWo[(hb * 4 + 3) * 256 + e]);
        row0[(2 | hb) ^ r] = vw;
        row1[(2 | hb) ^ r] = vw;
    }
    __syncthreads();

    // ---- Phase E: t-quad x e-chunk-in-wave; combine via shfl ----
    {
        const int lane = lt & 63;
        const int wv   = lt >> 6;        // wave id within half: 0..3
        const int hh   = wv & 1;         // head-quad
        const int tw   = wv >> 1;        // t-window
        const int t0   = lane & 15;
        const int c    = lane >> 4;      // e-chunk 0..3 (within wave)
        const int tb   = tw * 16 + t0;   // [0,32)
        const int ebase = c * 64;
        const float4* comboV = (const float4*)(&combo[half][0]);
        float aS[4][4], aM[4][4];
        #pragma unroll
        for (int k = 0; k < 4; ++k)
            #pragma unroll
            for (int j = 0; j < 4; ++j) { aS[k][j] = 0.f; aM[k][j] = 0.f; }
        const float xt0 = xs[half][tb];
        const float xt1 = xs[half][tb + 32];
        const float xt2 = xs[half][tb + 64];
        const float xt3 = xs[half][tb + 96];
        if (Lh > 64) {
            #pragma unroll 4
            for (int ee = 0; ee < 64; ++ee) E_ITER(4);
        } else if (Lh > 0) {
            // t >= 64 always masked in Phase F -> K=2 (t < 64 only)
            #pragma unroll 4
            for (int ee = 0; ee < 64; ++ee) E_ITER(2);
        }
        // sum across e-chunks c=0..3: lane = c*16+t0 -> shfl_down 32 then 16
        #pragma unroll
        for (int k = 0; k < 4; ++k)
            #pragma unroll
            for (int j = 0; j < 4; ++j) {
                float vS = aS[k][j], vM = aM[k][j];
                vS += __shfl_down(vS, 32, 64);
                vS += __shfl_down(vS, 16, 64);
                vM += __shfl_down(vM, 32, 64);
                vM += __shfl_down(vM, 16, 64);
                aS[k][j] = vS; aM[k][j] = vM;
            }
        __syncthreads();   // all combo-row reads done -> reuse region
        float* scF = &combo[half][0];        // sc[h*128+t]
        float* mvF = scF + 1024;             // mvb[h*128+t]
        if (c == 0) {
            #pragma unroll
            for (int k = 0; k < 4; ++k)
                #pragma unroll
                for (int j = 0; j < 4; ++j) {
                    const int h = hh * 4 + j;
                    scF[h * NT + tb + 32 * k] = aS[k][j];
                    mvF[h * NT + tb + 32 * k] = aM[k][j];
                }
        }
    }
    __syncthreads();

    // ---- qkx (post-E, into freed combo[half][2048..3072)): PEKT coalesced in t ----
    {
        const int h  = tid >> 6;             // 0..7
        const int tq = tid & 63;
        const float* pekt = ws + OFF_PEK;    // PEKT[j][t]
        const float4* qs40 = (const float4*)(qs[0] + h * 32);
        const float4* qs41 = (const float4*)(qs[1] + h * 32);
        float b00 = 0.f, b01 = 0.f, b10 = 0.f, b11 = 0.f;  // [wg][t-half]
        #pragma unroll
        for (int jq = 0; jq < 8; ++jq) {
            const float4 q0 = qs40[jq];
            const float4 q1 = qs41[jq];
            const float* pr = pekt + (h * 32 + jq * 4) * NT + tq;
            const float p00 = pr[0];          const float p01 = pr[64];
            const float p10 = pr[NT];         const float p11 = pr[NT + 64];
            const float p20 = pr[2 * NT];     const float p21 = pr[2 * NT + 64];
            const float p30 = pr[3 * NT];     const float p31 = pr[3 * NT + 64];
            b00 = fmaf(q0.x, p00, b00); b00 = fmaf(q0.y, p10, b00);
            b00 = fmaf(q0.z, p20, b00); b00 = fmaf(q0.w, p30, b00);
            b01 = fmaf(q0.x, p01, b01); b01 = fmaf(q0.y, p11, b01);
            b01 = fmaf(q0.z, p21, b01); b01 = fmaf(q0.w, p31, b01);
            b10 = fmaf(q1.x, p00, b10); b10 = fmaf(q1.y, p10, b10);
            b10 = fmaf(q1.z, p20, b10); b10 = fmaf(q1.w, p30, b10);
            b11 = fmaf(q1.x, p01, b11); b11 = fmaf(q1.y, p11, b11);
            b11 = fmaf(q1.z, p21, b11); b11 = fmaf(q1.w, p31, b11);
        }
        combo[0][2048 + h * NT + tq]      = b00;
        combo[0][2048 + h * NT + tq + 64] = b01;
        combo[1][2048 + h * NT + tq]      = b10;
        combo[1][2048 + h * NT + tq + 64] = b11;
    }
    __syncthreads();

    // ---- Phase F (per half): softmax over t<Lh with pe corrections ----
    if (Lh > 0) {
        const float* sc   = &combo[half][0];
        const float* mvb  = sc + 1024;
        const float* qkxp = sc + 2048;
        const float* pemv = ws + OFF_PEMV;
        const int wv = lt >> 6, lane = lt & 63;
        float wsum = 0.f;
        for (int hh2 = 0; hh2 < 2; ++hh2) {
            const int h = wv * 2 + hh2;
            float s1 = (lane < Lh) ? sc[h * NT + lane] + qkxp[h * NT + lane] : -3e38f;
            float s2 = (lane + 64 < Lh) ? sc[h * NT + 64 + lane] + qkxp[h * NT + 64 + lane] : -3e38f;
            float mx = fmaxf(s1, s2);
            #pragma unroll
            for (int off = 32; off > 0; off >>= 1)
                mx = fmaxf(mx, __shfl_down(mx, off, 64));
            mx = __shfl(mx, 0, 64);
            const float vbv = ws[OFF_EVA + ah * NH + h];
            float e1 = (lane < Lh) ? __expf(s1 - mx) : 0.f;
            float e2 = (lane + 64 < Lh) ? __expf(s2 - mx) : 0.f;
            float num = e1 * (mvb[h * NT + lane] + pemv[h * NT + lane] + vbv);
            num = fmaf(e2, mvb[h * NT + 64 + lane] + pemv[h * NT + 64 + lane] + vbv, num);
            float den = e1 + e2;
            #pragma unroll
            for (int off = 32; off > 0; off >>= 1) {
                num += __shfl_down(num, off, 64);
                den += __shfl_down(den, off, 64);
            }
            if (lane == 0) wsum += num / den;
        }
        if (lane == 0) red[half][wv] = wsum;
    }
    __syncthreads();
    if (lt == 0 && Lh > 0)
        atomicAdd(ws + OFF_SB + bh,
                  cstp[7] + red[half][0] + red[half][1] + red[half][2] + red[half][3]);
}

__global__ __launch_bounds__(64) void final_kernel(
    const float* __restrict__ statics, const int* __restrict__ lengths,
    const float* __restrict__ ws, float* __restrict__ out)
{
    const int b = threadIdx.x;   // 64 threads, one per batch
    const float* cst = ws + OFF_CST;
    int n = 0;
    for (int a = 0; a < NA; ++a)
        if (lengths[b * NA + a] > 0) ++n;
    float o = ws[OFF_SB + b] / ((float)n + 1e-9f);
    #pragma unroll
    for (int i = 0; i < NS; ++i)
        o = fmaf(statics[b * NS + i], cst[i], o);
    o += cst[6];
    out[b] = o;
}

extern "C" void kernel_launch(void* const* d_in, const int* in_sizes, int n_in,
                              void* d_out, int out_size, void* d_ws, size_t ws_size,
                              hipStream_t stream) {
    const float* data     = (const float*)d_in[0];
    // d_in[1] = time  (implied by mask; unused)
    const int*   mask     = (const int*)d_in[2];
    const float* statics  = (const float*)d_in[3];
    const float* W_embed  = (const float*)d_in[4];
    const float* b_embed  = (const float*)d_in[5];
    const float* E_var    = (const float*)d_in[6];
    const float* W_static = (const float*)d_in[7];
    const float* b_static = (const float*)d_in[8];
    const float* Wq       = (const float*)d_in[9];
    const float* bq       = (const float*)d_in[10];
    const float* Wk       = (const float*)d_in[11];
    // d_in[12] = bk (uniform over t -> cancels in softmax; unused)
    const float* Wv       = (const float*)d_in[13];
    const float* bv       = (const float*)d_in[14];
    const float* Wo       = (const float*)d_in[15];
    const float* bo       = (const float*)d_in[16];
    const float* Wg       = (const float*)d_in[17];
    const float* bg       = (const float*)d_in[18];
    float* out = (float*)d_out;
    float* ws  = (float*)d_ws;

    setup1_kernel<<<dim3(393), dim3(256), 0, stream>>>(Wk, Wv, Wo, Wg, bv, bo,
                                                       W_static, b_static, bg, E_var, ws);
    setup2_kernel<<<dim3(128), dim3(256), 0, stream>>>(Wk, ws);
    main_kernel<<<dim3(NB * NA / 2), dim3(512), 0, stream>>>(data, mask, W_embed, b_embed,
                                                             E_var, Wq, bq, ws);
    final_kernel<<<dim3(1), dim3(64), 0, stream>>>(statics, mask, ws, out);
}